// Round 1
// baseline (189.835 us; speedup 1.0000x reference)
//
#include <hip/hip_runtime.h>
#include <cstdint>
#include <cstddef>

namespace {

constexpr int kB = 16;
constexpr int kH = 512;
constexpr int kW = 512;
constexpr int kHW = kH * kW;
constexpr int kNS = 37632;     // NUM_POINTS * OVERSAMPLE
constexpr int kNUNC = 9408;    // 0.75 * NUM_POINTS
constexpr int kNRAND = 3136;
constexpr int kNPTS = 12544;
constexpr int kCandMax = 4096;
constexpr int kHist = 65536;

// workspace layout (bytes)
constexpr size_t OFF_PL    = 0;                                   // [B][NS] f32
constexpr size_t OFF_HIST  = OFF_PL + (size_t)kB * kNS * 4;       // [B][65536] u32
constexpr size_t OFF_SEL   = OFF_HIST + (size_t)kB * kHist * 4;   // [B][NS] u8
constexpr size_t OFF_CAND  = OFF_SEL + (size_t)kB * kNS;          // [B][CandMax] i32
constexpr size_t OFF_CCNT  = OFF_CAND + (size_t)kB * kCandMax * 4;// [B] i32 (padded 256)
constexpr size_t OFF_BINFO = OFF_CCNT + 256;                      // [B][8] i32
constexpr size_t OFF_ACC   = OFF_BINFO + (size_t)kB * 8 * 4;      // [B][9] f64
constexpr size_t OFF_BBOX  = OFF_ACC + (size_t)kB * 9 * 8;        // [B][4] i32
constexpr size_t OFF_BOXI  = OFF_BBOX + (size_t)kB * 4 * 4;       // [B][8] i32

} // namespace

__device__ __forceinline__ float sample_bilinear(const float* __restrict__ img,
                                                 float cx, float cy) {
  float x = cx * (float)kW - 0.5f;
  float y = cy * (float)kH - 0.5f;
  float x0f = floorf(x), y0f = floorf(y);
  float wx1 = x - x0f, wx0 = 1.0f - wx1;
  float wy1 = y - y0f, wy0 = 1.0f - wy1;
  int x0 = (int)x0f, y0 = (int)y0f;
  int x1 = x0 + 1, y1 = y0 + 1;
  int xc0 = min(max(x0, 0), kW - 1), xc1 = min(max(x1, 0), kW - 1);
  int yc0 = min(max(y0, 0), kH - 1), yc1 = min(max(y1, 0), kH - 1);
  float v00 = ((x0 >= 0) && (x0 < kW) && (y0 >= 0) && (y0 < kH)) ? img[yc0 * kW + xc0] : 0.0f;
  float v01 = ((x1 >= 0) && (x1 < kW) && (y0 >= 0) && (y0 < kH)) ? img[yc0 * kW + xc1] : 0.0f;
  float v10 = ((x0 >= 0) && (x0 < kW) && (y1 >= 0) && (y1 < kH)) ? img[yc1 * kW + xc0] : 0.0f;
  float v11 = ((x1 >= 0) && (x1 < kW) && (y1 >= 0) && (y1 < kH)) ? img[yc1 * kW + xc1] : 0.0f;
  return v00 * (wy0 * wx0) + v01 * (wy0 * wx1) + v10 * (wy1 * wx0) + v11 * (wy1 * wx1);
}

__device__ __forceinline__ float log_sigmoid_f(float x) {
  // min(x,0) - log1p(exp(-|x|))
  return fminf(x, 0.0f) - log1pf(expf(-fabsf(x)));
}

// ---- init small accumulators ----
__global__ __launch_bounds__(256) void init_kernel(double* acc, int* ccnt, int* bbox) {
  int t = threadIdx.x;
  for (int i = t; i < kB * 9; i += 256) acc[i] = 0.0;
  if (t < kB) ccnt[t] = 0;
  if (t < kB) {
    bbox[t * 4 + 0] = kW;   // xmin
    bbox[t * 4 + 1] = -1;   // xmax
    bbox[t * 4 + 2] = kH;   // ymin
    bbox[t * 4 + 3] = -1;   // ymax
  }
}

// ---- sample pred at oversampled coords ----
__global__ __launch_bounds__(256) void sample_os_kernel(const float* __restrict__ pred,
                                                        const float* __restrict__ coords,
                                                        float* __restrict__ pl) {
  int idx = blockIdx.x * 256 + threadIdx.x;
  if (idx >= kB * kNS) return;
  int b = idx / kNS;
  float cx = coords[(size_t)idx * 2 + 0];
  float cy = coords[(size_t)idx * 2 + 1];
  pl[idx] = sample_bilinear(pred + (size_t)b * kHW, cx, cy);
}

// ---- histogram of high 16 bits of |pl| ----
__global__ __launch_bounds__(256) void hist_hi_kernel(const float* __restrict__ pl,
                                                      unsigned* __restrict__ hist) {
  int idx = blockIdx.x * 256 + threadIdx.x;
  if (idx >= kB * kNS) return;
  int b = idx / kNS;
  unsigned bits = __float_as_uint(pl[idx]) & 0x7fffffffu;
  atomicAdd(&hist[(size_t)b * kHist + (bits >> 16)], 1u);
}

// ---- histogram of low 16 bits restricted to elems in high bin b1 ----
__global__ __launch_bounds__(256) void hist_lo_kernel(const float* __restrict__ pl,
                                                      const int* __restrict__ binfo,
                                                      unsigned* __restrict__ hist) {
  int idx = blockIdx.x * 256 + threadIdx.x;
  if (idx >= kB * kNS) return;
  int b = idx / kNS;
  unsigned bits = __float_as_uint(pl[idx]) & 0x7fffffffu;
  if ((int)(bits >> 16) == binfo[b * 8 + 0])
    atomicAdd(&hist[(size_t)b * kHist + (bits & 0xffffu)], 1u);
}

// ---- find bin containing the K-th smallest; phase 0: K=NUNC, phase 1: K=need1 ----
__global__ __launch_bounds__(256) void select_kernel(const unsigned* __restrict__ hist,
                                                     int* __restrict__ binfo, int phase) {
  int b = blockIdx.x;
  int t = threadIdx.x;
  const unsigned* h = hist + (size_t)b * kHist;
  __shared__ unsigned part[256];
  __shared__ unsigned seg[256];
  __shared__ int s_sidx;
  __shared__ unsigned s_cumbase;
  __shared__ int s_K;
  if (t == 0) s_K = (phase == 0) ? kNUNC : binfo[b * 8 + 1];
  unsigned s = 0;
  for (int k = 0; k < 256; ++k) s += h[t * 256 + k];
  part[t] = s;
  __syncthreads();
  if (t == 0) {
    unsigned K = (unsigned)s_K;
    unsigned cum = 0;
    int sidx = 255;
    for (int i = 0; i < 256; ++i) {
      if (cum + part[i] >= K) { sidx = i; break; }
      cum += part[i];
    }
    s_sidx = sidx;
    s_cumbase = cum;
  }
  __syncthreads();
  seg[t] = h[(size_t)s_sidx * 256 + t];
  __syncthreads();
  if (t == 0) {
    unsigned K = (unsigned)s_K;
    unsigned cum = s_cumbase;
    int j = 255;
    for (int i = 0; i < 256; ++i) {
      if (cum + seg[i] >= K) { j = i; break; }
      cum += seg[i];
    }
    int bin = s_sidx * 256 + j;
    if (phase == 0) {
      binfo[b * 8 + 0] = bin;              // b1
      binfo[b * 8 + 1] = (int)(K - cum);   // need1
    } else {
      binfo[b * 8 + 2] = (int)((((unsigned)binfo[b * 8 + 0]) << 16) | (unsigned)bin); // tbits
      binfo[b * 8 + 3] = (int)(K - cum);   // need_eq
    }
  }
}

// ---- mark selected (strictly below threshold); collect equal candidates ----
__global__ __launch_bounds__(256) void mark_kernel(const float* __restrict__ pl,
                                                   const int* __restrict__ binfo,
                                                   unsigned char* __restrict__ sel,
                                                   int* __restrict__ cand,
                                                   int* __restrict__ ccnt) {
  int idx = blockIdx.x * 256 + threadIdx.x;
  if (idx >= kB * kNS) return;
  int b = idx / kNS;
  int i = idx - b * kNS;
  unsigned bits = __float_as_uint(pl[idx]) & 0x7fffffffu;
  unsigned T = (unsigned)binfo[b * 8 + 2];
  unsigned char f = (bits < T) ? 1 : 0;
  if (bits == T) {
    int pos = atomicAdd(&ccnt[b], 1);
    if (pos < kCandMax) cand[b * kCandMax + pos] = i;
  }
  sel[idx] = f;
}

// ---- rank equal-valued candidates by index; select first need_eq ----
__global__ __launch_bounds__(256) void rank_kernel(const int* __restrict__ cand,
                                                   const int* __restrict__ ccnt,
                                                   const int* __restrict__ binfo,
                                                   unsigned char* __restrict__ sel) {
  int b = blockIdx.x;
  int n = min(ccnt[b], kCandMax);
  int need = binfo[b * 8 + 3];
  for (int j = threadIdx.x; j < n; j += blockDim.x) {
    int ij = cand[b * kCandMax + j];
    int r = 0;
    for (int k = 0; k < n; ++k) r += (cand[b * kCandMax + k] < ij) ? 1 : 0;
    if (r < need) sel[(size_t)b * kNS + ij] = 1;
  }
}

// ---- point CE + dice sums ----
__global__ __launch_bounds__(256) void pointloss_kernel(const float* __restrict__ pred,
                                                        const float* __restrict__ gt,
                                                        const float* __restrict__ coords_os,
                                                        const float* __restrict__ coords_rand,
                                                        const float* __restrict__ pl,
                                                        const unsigned char* __restrict__ sel,
                                                        double* __restrict__ acc) {
  constexpr int PB = 64;
  int b = blockIdx.x / PB;
  int c = blockIdx.x % PB;
  int t = threadIdx.x;
  const float* pred_b = pred + (size_t)b * kHW;
  const float* gt_b = gt + (size_t)b * kHW;
  float ce_s = 0.0f, p_s = 0.0f, t_s = 0.0f, pt_s = 0.0f;
  const int total = kNS + kNRAND;
  for (int e = c * 256 + t; e < total; e += PB * 256) {
    float cx, cy, z;
    if (e < kNS) {
      if (!sel[(size_t)b * kNS + e]) continue;
      cx = coords_os[((size_t)b * kNS + e) * 2 + 0];
      cy = coords_os[((size_t)b * kNS + e) * 2 + 1];
      z = pl[(size_t)b * kNS + e];
    } else {
      int j = e - kNS;
      cx = coords_rand[((size_t)b * kNRAND + j) * 2 + 0];
      cy = coords_rand[((size_t)b * kNRAND + j) * 2 + 1];
      z = sample_bilinear(pred_b, cx, cy);
    }
    float tt = sample_bilinear(gt_b, cx, cy);
    float ce = fmaxf(z, 0.0f) - z * tt + log1pf(expf(-fabsf(z)));
    float p = 1.0f / (1.0f + expf(-z));
    ce_s += ce; p_s += p; t_s += tt; pt_s += p * tt;
  }
  __shared__ float red[4][256];
  red[0][t] = ce_s; red[1][t] = p_s; red[2][t] = t_s; red[3][t] = pt_s;
  __syncthreads();
  for (int s = 128; s > 0; s >>= 1) {
    if (t < s) {
      red[0][t] += red[0][t + s];
      red[1][t] += red[1][t + s];
      red[2][t] += red[2][t + s];
      red[3][t] += red[3][t + s];
    }
    __syncthreads();
  }
  if (t == 0) {
    atomicAdd(&acc[b * 9 + 0], (double)red[0][0]);
    atomicAdd(&acc[b * 9 + 1], (double)red[1][0]);
    atomicAdd(&acc[b * 9 + 2], (double)red[2][0]);
    atomicAdd(&acc[b * 9 + 3], (double)red[3][0]);
  }
}

// ---- bbox of sigmoid(pred) > 0.5 ----
__global__ __launch_bounds__(256) void bbox_kernel(const float* __restrict__ pred,
                                                   int* __restrict__ bbox) {
  constexpr int PB = 32;
  constexpr int CHUNK = kHW / PB; // 8192
  int b = blockIdx.x / PB;
  int c = blockIdx.x % PB;
  int t = threadIdx.x;
  const float* pred_b = pred + (size_t)b * kHW;
  int xmn = kW, xmx = -1, ymn = kH, ymx = -1;
  int start = c * CHUNK;
  for (int p = start + t; p < start + CHUNK; p += 256) {
    float z = pred_b[p];
    float sg = 1.0f / (1.0f + expf(-z));
    if (sg > 0.5f) {
      int x = p & (kW - 1);
      int y = p >> 9;
      xmn = min(xmn, x); xmx = max(xmx, x);
      ymn = min(ymn, y); ymx = max(ymx, y);
    }
  }
  __shared__ int r0[256], r1[256], r2[256], r3[256];
  r0[t] = xmn; r1[t] = xmx; r2[t] = ymn; r3[t] = ymx;
  __syncthreads();
  for (int s = 128; s > 0; s >>= 1) {
    if (t < s) {
      r0[t] = min(r0[t], r0[t + s]);
      r1[t] = max(r1[t], r1[t + s]);
      r2[t] = min(r2[t], r2[t + s]);
      r3[t] = max(r3[t], r3[t + s]);
    }
    __syncthreads();
  }
  if (t == 0) {
    atomicMin(&bbox[b * 4 + 0], r0[0]);
    atomicMax(&bbox[b * 4 + 1], r1[0]);
    atomicMin(&bbox[b * 4 + 2], r2[0]);
    atomicMax(&bbox[b * 4 + 3], r3[0]);
  }
}

// ---- box bounds per batch ----
__global__ __launch_bounds__(64) void boxcalc_kernel(const int* __restrict__ bbox,
                                                     int* __restrict__ boxi) {
  int t = threadIdx.x;
  if (t >= kB) return;
  int xmn = bbox[t * 4 + 0], xmx = bbox[t * 4 + 1];
  int ymn = bbox[t * 4 + 2], ymx = bbox[t * 4 + 3];
  bool empty = (xmx < 0);
  int x1 = empty ? 0 : xmn;
  int x2 = empty ? (kW - 1) : xmx;
  int y1 = empty ? 0 : ymn;
  int y2 = empty ? (kH - 1) : ymx;
  int x2i = min(x2, kW - 1);
  int y2i = min(y2, kH - 1);
  int valid = ((x2i > x1) && (y2i > y1)) ? 1 : 0;
  boxi[t * 8 + 0] = x1;
  boxi[t * 8 + 1] = y1;
  boxi[t * 8 + 2] = x2i;
  boxi[t * 8 + 3] = y2i;
  boxi[t * 8 + 4] = valid;
}

// ---- region BCE + dice sums ----
__global__ __launch_bounds__(256) void region_kernel(const float* __restrict__ pred,
                                                     const float* __restrict__ gt,
                                                     const int* __restrict__ boxi,
                                                     double* __restrict__ acc) {
  constexpr int PB = 64;
  constexpr int CHUNK = kHW / PB; // 4096
  int b = blockIdx.x / PB;
  int c = blockIdx.x % PB;
  int t = threadIdx.x;
  const float* pred_b = pred + (size_t)b * kHW;
  const float* gt_b = gt + (size_t)b * kHW;
  int x1 = boxi[b * 8 + 0], y1 = boxi[b * 8 + 1];
  int x2 = boxi[b * 8 + 2], y2 = boxi[b * 8 + 3];
  int valid = boxi[b * 8 + 4];
  float wsum = 0.0f, bcew = 0.0f, inter = 0.0f, pw = 0.0f, gw = 0.0f;
  int start = c * CHUNK;
  for (int p = start + t; p < start + CHUNK; p += 256) {
    int x = p & (kW - 1);
    int y = p >> 9;
    float box = (valid && x >= x1 && x <= x2 && y >= y1 && y <= y2) ? 1.0f : 0.0f;
    float w = box * 2.0f + (1.0f - box) * 0.5f;
    float z = pred_b[p];
    float g = gt_b[p];
    float logp = log_sigmoid_f(z);
    float log1mp = log_sigmoid_f(-z);
    float bce = -(g * logp + (1.0f - g) * log1mp);
    float pp = 1.0f / (1.0f + expf(-z));
    wsum += w;
    bcew += bce * w;
    inter += pp * g * w;
    pw += pp * w;
    gw += g * w;
  }
  __shared__ float red[5][256];
  red[0][t] = wsum; red[1][t] = bcew; red[2][t] = inter; red[3][t] = pw; red[4][t] = gw;
  __syncthreads();
  for (int s = 128; s > 0; s >>= 1) {
    if (t < s) {
      for (int q = 0; q < 5; ++q) red[q][t] += red[q][t + s];
    }
    __syncthreads();
  }
  if (t == 0) {
    atomicAdd(&acc[b * 9 + 4], (double)red[0][0]);
    atomicAdd(&acc[b * 9 + 5], (double)red[1][0]);
    atomicAdd(&acc[b * 9 + 6], (double)red[2][0]);
    atomicAdd(&acc[b * 9 + 7], (double)red[3][0]);
    atomicAdd(&acc[b * 9 + 8], (double)red[4][0]);
  }
}

// ---- finalize ----
__global__ __launch_bounds__(64) void finalize_kernel(const double* __restrict__ acc,
                                                      float* __restrict__ out) {
  if (threadIdx.x == 0) {
    double lm = 0.0, ld = 0.0, lrb = 0.0, lrd = 0.0;
    for (int b = 0; b < kB; ++b) {
      const double* a = acc + b * 9;
      lm += a[0] / (double)kNPTS;
      ld += 1.0 - (2.0 * a[3] + 1.0) / (a[1] + a[2] + 1.0);
      double ws = a[4] > 1e-6 ? a[4] : 1e-6;
      lrb += a[5] / ws;
      lrd += 1.0 - (2.0 * a[6] + 1.0) / (a[7] + a[8] + 1.0);
    }
    out[0] = (float)(lm / 16.0);
    out[1] = (float)(ld / 16.0);
    out[2] = (float)(lrb / 16.0);
    out[3] = (float)(lrd / 16.0);
  }
}

extern "C" void kernel_launch(void* const* d_in, const int* in_sizes, int n_in,
                              void* d_out, int out_size, void* d_ws, size_t ws_size,
                              hipStream_t stream) {
  const float* pred = (const float*)d_in[0];
  const float* gt = (const float*)d_in[1];
  const float* coords_os = (const float*)d_in[2];
  const float* coords_rand = (const float*)d_in[3];
  float* out = (float*)d_out;
  char* ws = (char*)d_ws;

  float* pl = (float*)(ws + OFF_PL);
  unsigned* hist = (unsigned*)(ws + OFF_HIST);
  unsigned char* sel = (unsigned char*)(ws + OFF_SEL);
  int* cand = (int*)(ws + OFF_CAND);
  int* ccnt = (int*)(ws + OFF_CCNT);
  int* binfo = (int*)(ws + OFF_BINFO);
  double* acc = (double*)(ws + OFF_ACC);
  int* bbox = (int*)(ws + OFF_BBOX);
  int* boxi = (int*)(ws + OFF_BOXI);

  const int nElems = kB * kNS;               // 602112
  const int gridE = (nElems + 255) / 256;    // 2352

  hipMemsetAsync(hist, 0, (size_t)kB * kHist * 4, stream);
  init_kernel<<<1, 256, 0, stream>>>(acc, ccnt, bbox);
  sample_os_kernel<<<gridE, 256, 0, stream>>>(pred, coords_os, pl);
  hist_hi_kernel<<<gridE, 256, 0, stream>>>(pl, hist);
  select_kernel<<<kB, 256, 0, stream>>>(hist, binfo, 0);
  hipMemsetAsync(hist, 0, (size_t)kB * kHist * 4, stream);
  hist_lo_kernel<<<gridE, 256, 0, stream>>>(pl, binfo, hist);
  select_kernel<<<kB, 256, 0, stream>>>(hist, binfo, 1);
  mark_kernel<<<gridE, 256, 0, stream>>>(pl, binfo, sel, cand, ccnt);
  rank_kernel<<<kB, 256, 0, stream>>>(cand, ccnt, binfo, sel);
  pointloss_kernel<<<kB * 64, 256, 0, stream>>>(pred, gt, coords_os, coords_rand, pl, sel, acc);
  bbox_kernel<<<kB * 32, 256, 0, stream>>>(pred, bbox);
  boxcalc_kernel<<<1, 64, 0, stream>>>(bbox, boxi);
  region_kernel<<<kB * 64, 256, 0, stream>>>(pred, gt, boxi, acc);
  finalize_kernel<<<1, 64, 0, stream>>>(acc, out);
}

// Round 2
// 155.785 us; speedup vs baseline: 1.2186x; 1.2186x over previous
//
#include <hip/hip_runtime.h>
#include <cstdint>
#include <cstddef>

namespace {

constexpr int kB = 16;
constexpr int kH = 512;
constexpr int kW = 512;
constexpr int kHW = kH * kW;
constexpr int kNS = 37632;     // NUM_POINTS * OVERSAMPLE
constexpr int kNUNC = 9408;    // 0.75 * NUM_POINTS
constexpr int kNRAND = 3136;
constexpr int kNPTS = 12544;

// workspace layout (bytes)
constexpr size_t OFF_PL   = 0;                                  // [B][NS] f32
constexpr size_t OFF_SEL  = OFF_PL + (size_t)kB * kNS * 4;      // [B][NS] u8
constexpr size_t OFF_ACC  = OFF_SEL + (size_t)kB * kNS;         // [B][9] f64  (8-aligned)
constexpr size_t OFF_BBOX = OFF_ACC + (size_t)kB * 9 * 8;       // [B][4] i32

} // namespace

__device__ __forceinline__ float sample_bilinear(const float* __restrict__ img,
                                                 float cx, float cy) {
  float x = cx * (float)kW - 0.5f;
  float y = cy * (float)kH - 0.5f;
  float x0f = floorf(x), y0f = floorf(y);
  float wx1 = x - x0f, wx0 = 1.0f - wx1;
  float wy1 = y - y0f, wy0 = 1.0f - wy1;
  int x0 = (int)x0f, y0 = (int)y0f;
  int x1 = x0 + 1, y1 = y0 + 1;
  int xc0 = min(max(x0, 0), kW - 1), xc1 = min(max(x1, 0), kW - 1);
  int yc0 = min(max(y0, 0), kH - 1), yc1 = min(max(y1, 0), kH - 1);
  float v00 = ((x0 >= 0) && (x0 < kW) && (y0 >= 0) && (y0 < kH)) ? img[yc0 * kW + xc0] : 0.0f;
  float v01 = ((x1 >= 0) && (x1 < kW) && (y0 >= 0) && (y0 < kH)) ? img[yc0 * kW + xc1] : 0.0f;
  float v10 = ((x0 >= 0) && (x0 < kW) && (y1 >= 0) && (y1 < kH)) ? img[yc1 * kW + xc0] : 0.0f;
  float v11 = ((x1 >= 0) && (x1 < kW) && (y1 >= 0) && (y1 < kH)) ? img[yc1 * kW + xc1] : 0.0f;
  return v00 * (wy0 * wx0) + v01 * (wy0 * wx1) + v10 * (wy1 * wx0) + v11 * (wy1 * wx1);
}

// ---- sample pred at oversampled coords; block 0 also inits acc/bbox ----
__global__ __launch_bounds__(256) void sample_os_kernel(const float* __restrict__ pred,
                                                        const float* __restrict__ coords,
                                                        float* __restrict__ pl,
                                                        double* __restrict__ acc,
                                                        int* __restrict__ bbox) {
  if (blockIdx.x == 0) {
    int t = threadIdx.x;
    if (t < kB * 9) acc[t] = 0.0;
    if (t >= 192 && t < 192 + kB) {
      int b = t - 192;
      bbox[b * 4 + 0] = kW;   // xmin
      bbox[b * 4 + 1] = -1;   // xmax
      bbox[b * 4 + 2] = kH;   // ymin
      bbox[b * 4 + 3] = -1;   // ymax
    }
  }
  int idx = blockIdx.x * 256 + threadIdx.x;
  if (idx >= kB * kNS) return;
  int b = idx / kNS;
  float2 c = *(const float2*)&coords[(size_t)idx * 2];
  pl[idx] = sample_bilinear(pred + (size_t)b * kHW, c.x, c.y);
}

// ---- fused exact top-k select: one block per batch ----
__global__ __launch_bounds__(1024) void select_kernel(const float* __restrict__ pl,
                                                      unsigned char* __restrict__ sel) {
  constexpr int C = 37;  // ceil(37632/1024)
  int b = blockIdx.x;
  int t = threadIdx.x;
  const float* pl_b = pl + (size_t)b * kNS;
  unsigned char* sel_b = sel + (size_t)b * kNS;

  unsigned v[C];
  int base = t * C;
#pragma unroll
  for (int j = 0; j < C; ++j) {
    int idx = base + j;
    v[j] = (idx < kNS) ? (__float_as_uint(pl_b[idx]) & 0x7fffffffu) : 0xffffffffu;
  }

  __shared__ unsigned hist[256];
  __shared__ unsigned scan[1024];
  __shared__ unsigned s_prefix, s_krem;
  if (t == 0) { s_prefix = 0u; s_krem = (unsigned)kNUNC; }
  if (t < 256) hist[t] = 0u;
  __syncthreads();

  unsigned prefix = 0u;
#pragma unroll
  for (int r = 0; r < 4; ++r) {
    const int shift = 24 - 8 * r;
#pragma unroll
    for (int j = 0; j < C; ++j) {
      unsigned u = v[j];
      bool m = (r == 0) ? (u <= 0x7fffffffu) : ((u >> (shift + 8)) == prefix);
      if (m) atomicAdd(&hist[(u >> shift) & 0xffu], 1u);
    }
    __syncthreads();
    if (t == 0) {
      unsigned K = s_krem;
      unsigned cum = 0;
      int sbin = 255;
      for (int i = 0; i < 256; ++i) {
        unsigned h = hist[i];
        if (cum + h >= K) { sbin = i; break; }
        cum += h;
      }
      s_prefix = (s_prefix << 8) | (unsigned)sbin;
      s_krem = K - cum;
    }
    __syncthreads();
    prefix = s_prefix;
    if (t < 256) hist[t] = 0u;
    __syncthreads();
  }

  unsigned T = prefix;            // exact 31-bit threshold pattern
  unsigned need = s_krem;         // #equal-to-T to take, lowest index first

  unsigned cnt = 0;
#pragma unroll
  for (int j = 0; j < C; ++j) cnt += (v[j] == T) ? 1u : 0u;
  scan[t] = cnt;
  __syncthreads();
  for (int off = 1; off < 1024; off <<= 1) {
    unsigned val = (t >= off) ? scan[t - off] : 0u;
    __syncthreads();
    scan[t] += val;
    __syncthreads();
  }
  unsigned run = scan[t] - cnt;   // exclusive prefix of equals before my chunk

#pragma unroll
  for (int j = 0; j < C; ++j) {
    int idx = base + j;
    if (idx < kNS) {
      unsigned u = v[j];
      unsigned char s = (u < T) ? 1 : 0;
      if (u == T) { s = (run < need) ? 1 : 0; run++; }
      sel_b[idx] = s;
    }
  }
}

// ---- point CE + dice sums ----
__global__ __launch_bounds__(256) void pointloss_kernel(const float* __restrict__ pred,
                                                        const float* __restrict__ gt,
                                                        const float* __restrict__ coords_os,
                                                        const float* __restrict__ coords_rand,
                                                        const float* __restrict__ pl,
                                                        const unsigned char* __restrict__ sel,
                                                        double* __restrict__ acc) {
  constexpr int PB = 32;
  int b = blockIdx.x / PB;
  int c = blockIdx.x % PB;
  int t = threadIdx.x;
  const float* pred_b = pred + (size_t)b * kHW;
  const float* gt_b = gt + (size_t)b * kHW;
  float ce_s = 0.0f, p_s = 0.0f, t_s = 0.0f, pt_s = 0.0f;
  const int total = kNS + kNRAND;
  for (int e = c * 256 + t; e < total; e += PB * 256) {
    float cx, cy, z;
    if (e < kNS) {
      if (!sel[(size_t)b * kNS + e]) continue;
      float2 cc = *(const float2*)&coords_os[((size_t)b * kNS + e) * 2];
      cx = cc.x; cy = cc.y;
      z = pl[(size_t)b * kNS + e];
    } else {
      int j = e - kNS;
      float2 cc = *(const float2*)&coords_rand[((size_t)b * kNRAND + j) * 2];
      cx = cc.x; cy = cc.y;
      z = sample_bilinear(pred_b, cx, cy);
    }
    float tt = sample_bilinear(gt_b, cx, cy);
    float ce = fmaxf(z, 0.0f) - z * tt + log1pf(expf(-fabsf(z)));
    float a = expf(-fabsf(z));
    float inv = 1.0f / (1.0f + a);
    float p = (z >= 0.0f) ? inv : a * inv;
    ce_s += ce; p_s += p; t_s += tt; pt_s += p * tt;
  }
  __shared__ float red[4][256];
  red[0][t] = ce_s; red[1][t] = p_s; red[2][t] = t_s; red[3][t] = pt_s;
  __syncthreads();
  for (int s = 128; s > 0; s >>= 1) {
    if (t < s) {
      red[0][t] += red[0][t + s];
      red[1][t] += red[1][t + s];
      red[2][t] += red[2][t + s];
      red[3][t] += red[3][t + s];
    }
    __syncthreads();
  }
  if (t == 0) {
    atomicAdd(&acc[b * 9 + 0], (double)red[0][0]);
    atomicAdd(&acc[b * 9 + 1], (double)red[1][0]);
    atomicAdd(&acc[b * 9 + 2], (double)red[2][0]);
    atomicAdd(&acc[b * 9 + 3], (double)red[3][0]);
  }
}

// ---- bbox of pred > 0 (== sigmoid > 0.5), float4 loads ----
__global__ __launch_bounds__(256) void bbox_kernel(const float* __restrict__ pred,
                                                   int* __restrict__ bbox) {
  constexpr int PB = 16;
  constexpr int CHUNK4 = kHW / PB / 4;  // 4096 float4 per block
  int b = blockIdx.x / PB;
  int c = blockIdx.x % PB;
  int t = threadIdx.x;
  const float4* pred4 = (const float4*)(pred + (size_t)b * kHW) + (size_t)c * CHUNK4;
  int pbase = c * CHUNK4 * 4;
  int xmn = kW, xmx = -1, ymn = kH, ymx = -1;
  for (int i = t; i < CHUNK4; i += 256) {
    float4 z = pred4[i];
    int p = pbase + i * 4;
    int y = p >> 9;
    int x0 = p & (kW - 1);
    if (z.x > 0.0f) { xmn = min(xmn, x0);     xmx = max(xmx, x0);     ymn = min(ymn, y); ymx = max(ymx, y); }
    if (z.y > 0.0f) { xmn = min(xmn, x0 + 1); xmx = max(xmx, x0 + 1); ymn = min(ymn, y); ymx = max(ymx, y); }
    if (z.z > 0.0f) { xmn = min(xmn, x0 + 2); xmx = max(xmx, x0 + 2); ymn = min(ymn, y); ymx = max(ymx, y); }
    if (z.w > 0.0f) { xmn = min(xmn, x0 + 3); xmx = max(xmx, x0 + 3); ymn = min(ymn, y); ymx = max(ymx, y); }
  }
  __shared__ int r0[256], r1[256], r2[256], r3[256];
  r0[t] = xmn; r1[t] = xmx; r2[t] = ymn; r3[t] = ymx;
  __syncthreads();
  for (int s = 128; s > 0; s >>= 1) {
    if (t < s) {
      r0[t] = min(r0[t], r0[t + s]);
      r1[t] = max(r1[t], r1[t + s]);
      r2[t] = min(r2[t], r2[t + s]);
      r3[t] = max(r3[t], r3[t + s]);
    }
    __syncthreads();
  }
  if (t == 0) {
    atomicMin(&bbox[b * 4 + 0], r0[0]);
    atomicMax(&bbox[b * 4 + 1], r1[0]);
    atomicMin(&bbox[b * 4 + 2], r2[0]);
    atomicMax(&bbox[b * 4 + 3], r3[0]);
  }
}

// ---- region BCE + dice sums (box bounds derived inline from bbox) ----
__global__ __launch_bounds__(256) void region_kernel(const float* __restrict__ pred,
                                                     const float* __restrict__ gt,
                                                     const int* __restrict__ bbox,
                                                     double* __restrict__ acc) {
  constexpr int PB = 64;
  constexpr int CHUNK4 = kHW / PB / 4;  // 1024 float4 per block
  int b = blockIdx.x / PB;
  int c = blockIdx.x % PB;
  int t = threadIdx.x;
  const float4* pred4 = (const float4*)(pred + (size_t)b * kHW) + (size_t)c * CHUNK4;
  const float4* gt4 = (const float4*)(gt + (size_t)b * kHW) + (size_t)c * CHUNK4;
  int xmn = bbox[b * 4 + 0], xmx = bbox[b * 4 + 1];
  int ymn = bbox[b * 4 + 2], ymx = bbox[b * 4 + 3];
  bool empty = (xmx < 0);
  int x1 = empty ? 0 : xmn;
  int x2 = min(empty ? (kW - 1) : xmx, kW - 1);
  int y1 = empty ? 0 : ymn;
  int y2 = min(empty ? (kH - 1) : ymx, kH - 1);
  bool valid = (x2 > x1) && (y2 > y1);

  int pbase = c * CHUNK4 * 4;
  float wsum = 0.0f, bcew = 0.0f, inter = 0.0f, pw = 0.0f, gw = 0.0f;
  for (int i = t; i < CHUNK4; i += 256) {
    float4 zv = pred4[i];
    float4 gv = gt4[i];
    int p = pbase + i * 4;
    int y = p >> 9;
    int x0 = p & (kW - 1);
    bool iny = valid && (y >= y1) && (y <= y2);
#pragma unroll
    for (int l = 0; l < 4; ++l) {
      float z = (l == 0) ? zv.x : (l == 1) ? zv.y : (l == 2) ? zv.z : zv.w;
      float g = (l == 0) ? gv.x : (l == 1) ? gv.y : (l == 2) ? gv.z : gv.w;
      int x = x0 + l;
      float w = (iny && x >= x1 && x <= x2) ? 2.0f : 0.5f;
      float a = expf(-fabsf(z));
      float sp = fmaxf(-z, 0.0f) + log1pf(a);   // softplus(-z) = -log_sigmoid(z)
      float bce = sp + (1.0f - g) * z;          // g*sp + (1-g)*(z+sp)
      float inv = 1.0f / (1.0f + a);
      float pp = (z >= 0.0f) ? inv : a * inv;
      wsum += w;
      bcew += bce * w;
      inter += pp * g * w;
      pw += pp * w;
      gw += g * w;
    }
  }
  __shared__ float red[5][256];
  red[0][t] = wsum; red[1][t] = bcew; red[2][t] = inter; red[3][t] = pw; red[4][t] = gw;
  __syncthreads();
  for (int s = 128; s > 0; s >>= 1) {
    if (t < s) {
#pragma unroll
      for (int q = 0; q < 5; ++q) red[q][t] += red[q][t + s];
    }
    __syncthreads();
  }
  if (t == 0) {
    atomicAdd(&acc[b * 9 + 4], (double)red[0][0]);
    atomicAdd(&acc[b * 9 + 5], (double)red[1][0]);
    atomicAdd(&acc[b * 9 + 6], (double)red[2][0]);
    atomicAdd(&acc[b * 9 + 7], (double)red[3][0]);
    atomicAdd(&acc[b * 9 + 8], (double)red[4][0]);
  }
}

// ---- finalize ----
__global__ __launch_bounds__(64) void finalize_kernel(const double* __restrict__ acc,
                                                      float* __restrict__ out) {
  if (threadIdx.x == 0) {
    double lm = 0.0, ld = 0.0, lrb = 0.0, lrd = 0.0;
    for (int b = 0; b < kB; ++b) {
      const double* a = acc + b * 9;
      lm += a[0] / (double)kNPTS;
      ld += 1.0 - (2.0 * a[3] + 1.0) / (a[1] + a[2] + 1.0);
      double ws = a[4] > 1e-6 ? a[4] : 1e-6;
      lrb += a[5] / ws;
      lrd += 1.0 - (2.0 * a[6] + 1.0) / (a[7] + a[8] + 1.0);
    }
    out[0] = (float)(lm / 16.0);
    out[1] = (float)(ld / 16.0);
    out[2] = (float)(lrb / 16.0);
    out[3] = (float)(lrd / 16.0);
  }
}

extern "C" void kernel_launch(void* const* d_in, const int* in_sizes, int n_in,
                              void* d_out, int out_size, void* d_ws, size_t ws_size,
                              hipStream_t stream) {
  const float* pred = (const float*)d_in[0];
  const float* gt = (const float*)d_in[1];
  const float* coords_os = (const float*)d_in[2];
  const float* coords_rand = (const float*)d_in[3];
  float* out = (float*)d_out;
  char* ws = (char*)d_ws;

  float* pl = (float*)(ws + OFF_PL);
  unsigned char* sel = (unsigned char*)(ws + OFF_SEL);
  double* acc = (double*)(ws + OFF_ACC);
  int* bbox = (int*)(ws + OFF_BBOX);

  const int nElems = kB * kNS;               // 602112
  const int gridE = (nElems + 255) / 256;    // 2352

  sample_os_kernel<<<gridE, 256, 0, stream>>>(pred, coords_os, pl, acc, bbox);
  select_kernel<<<kB, 1024, 0, stream>>>(pl, sel);
  pointloss_kernel<<<kB * 32, 256, 0, stream>>>(pred, gt, coords_os, coords_rand, pl, sel, acc);
  bbox_kernel<<<kB * 16, 256, 0, stream>>>(pred, bbox);
  region_kernel<<<kB * 64, 256, 0, stream>>>(pred, gt, bbox, acc);
  finalize_kernel<<<1, 64, 0, stream>>>(acc, out);
}

// Round 3
// 86.441 us; speedup vs baseline: 2.1961x; 1.8022x over previous
//
#include <hip/hip_runtime.h>
#include <cstdint>
#include <cstddef>

namespace {

constexpr int kB = 16;
constexpr int kH = 512;
constexpr int kW = 512;
constexpr int kHW = kH * kW;
constexpr int kNS = 37632;     // NUM_POINTS * OVERSAMPLE
constexpr int kNUNC = 9408;    // 0.75 * NUM_POINTS
constexpr int kNRAND = 3136;
constexpr int kNPTS = 12544;
constexpr int kBins = 16384;   // 14-bit bins: exp(8) + mantissa(6)
constexpr int kPLB = 32;       // pointloss blocks per batch
constexpr int kRGB = 64;       // region blocks per batch
constexpr int kBXB = 16;       // bbox partial blocks per batch
constexpr int kSampleBlocks = (kB * kNS) / 256;  // 2352

// workspace layout (bytes)
constexpr size_t OFF_PL  = 0;                                   // [B][NS] f32
constexpr size_t OFF_SEL = OFF_PL + (size_t)kB * kNS * 4;       // [B][NS] u8
constexpr size_t OFF_BBP = OFF_SEL + (size_t)kB * kNS;          // [B][16][4] i32 partial bbox
constexpr size_t OFF_PLP = OFF_BBP + (size_t)kB * kBXB * 4 * 4; // [B][32][4] f32 partial point sums
constexpr size_t OFF_RGP = OFF_PLP + (size_t)kB * kPLB * 4 * 4; // [B][64][5] f32 partial region sums

} // namespace

__device__ __forceinline__ float sample_bilinear(const float* __restrict__ img,
                                                 float cx, float cy) {
  float x = cx * (float)kW - 0.5f;
  float y = cy * (float)kH - 0.5f;
  float x0f = floorf(x), y0f = floorf(y);
  float wx1 = x - x0f, wx0 = 1.0f - wx1;
  float wy1 = y - y0f, wy0 = 1.0f - wy1;
  int x0 = (int)x0f, y0 = (int)y0f;
  int x1 = x0 + 1, y1 = y0 + 1;
  int xc0 = min(max(x0, 0), kW - 1), xc1 = min(max(x1, 0), kW - 1);
  int yc0 = min(max(y0, 0), kH - 1), yc1 = min(max(y1, 0), kH - 1);
  float v00 = ((x0 >= 0) && (x0 < kW) && (y0 >= 0) && (y0 < kH)) ? img[yc0 * kW + xc0] : 0.0f;
  float v01 = ((x1 >= 0) && (x1 < kW) && (y0 >= 0) && (y0 < kH)) ? img[yc0 * kW + xc1] : 0.0f;
  float v10 = ((x0 >= 0) && (x0 < kW) && (y1 >= 0) && (y1 < kH)) ? img[yc1 * kW + xc0] : 0.0f;
  float v11 = ((x1 >= 0) && (x1 < kW) && (y1 >= 0) && (y1 < kH)) ? img[yc1 * kW + xc1] : 0.0f;
  return v00 * (wy0 * wx0) + v01 * (wy0 * wx1) + v10 * (wy1 * wx0) + v11 * (wy1 * wx1);
}

// ---- fused: sample pred at oversampled coords (blocks < 2352)
//      + bbox partial min/max of pred>0 (blocks 2352..2607, plain stores) ----
__global__ __launch_bounds__(256) void sample_bbox_kernel(const float* __restrict__ pred,
                                                          const float* __restrict__ coords,
                                                          float* __restrict__ pl,
                                                          int* __restrict__ bbp) {
  __shared__ int r0[256], r1[256], r2[256], r3[256];
  int blk = blockIdx.x;
  int t = threadIdx.x;
  if (blk < kSampleBlocks) {
    int idx = blk * 256 + t;
    int b = idx / kNS;
    float2 c = *(const float2*)&coords[(size_t)idx * 2];
    pl[idx] = sample_bilinear(pred + (size_t)b * kHW, c.x, c.y);
    return;
  }
  int bb = blk - kSampleBlocks;
  int b = bb / kBXB;
  int c = bb % kBXB;
  constexpr int CHUNK4 = kHW / kBXB / 4;  // 4096 float4
  const float4* pred4 = (const float4*)(pred + (size_t)b * kHW) + (size_t)c * CHUNK4;
  int pbase = c * CHUNK4 * 4;
  int xmn = kW, xmx = -1, ymn = kH, ymx = -1;
  for (int i = t; i < CHUNK4; i += 256) {
    float4 z = pred4[i];
    int p = pbase + i * 4;
    int y = p >> 9;
    int x0 = p & (kW - 1);
    if (z.x > 0.0f) { xmn = min(xmn, x0);     xmx = max(xmx, x0);     ymn = min(ymn, y); ymx = max(ymx, y); }
    if (z.y > 0.0f) { xmn = min(xmn, x0 + 1); xmx = max(xmx, x0 + 1); ymn = min(ymn, y); ymx = max(ymx, y); }
    if (z.z > 0.0f) { xmn = min(xmn, x0 + 2); xmx = max(xmx, x0 + 2); ymn = min(ymn, y); ymx = max(ymx, y); }
    if (z.w > 0.0f) { xmn = min(xmn, x0 + 3); xmx = max(xmx, x0 + 3); ymn = min(ymn, y); ymx = max(ymx, y); }
  }
  r0[t] = xmn; r1[t] = xmx; r2[t] = ymn; r3[t] = ymx;
  __syncthreads();
  for (int s = 128; s > 0; s >>= 1) {
    if (t < s) {
      r0[t] = min(r0[t], r0[t + s]);
      r1[t] = max(r1[t], r1[t + s]);
      r2[t] = min(r2[t], r2[t + s]);
      r3[t] = max(r3[t], r3[t + s]);
    }
    __syncthreads();
  }
  if (t == 0) {
    int* o = bbp + ((size_t)b * kBXB + c) * 4;
    o[0] = r0[0]; o[1] = r1[0]; o[2] = r2[0]; o[3] = r3[0];
  }
}

// ---- per-batch selection: 14-bit LDS histogram + boundary-bin index fill ----
__global__ __launch_bounds__(1024) void select_kernel(const float* __restrict__ pl,
                                                      unsigned char* __restrict__ sel) {
  constexpr int C = 37;            // ceil(37632/1024)
  constexpr int CAP = 1024;        // candidate list capacity
  int b = blockIdx.x;
  int t = threadIdx.x;
  const float* pl_b = pl + (size_t)b * kNS;
  unsigned char* sel_b = sel + (size_t)b * kNS;

  __shared__ unsigned hist[kBins];     // 64 KB
  __shared__ unsigned scan[1024];      // 4 KB
  __shared__ int cand[CAP];            // 4 KB
  __shared__ int s_bstar, s_need, s_ccnt, s_round;

  for (int i = t; i < kBins; i += 1024) hist[i] = 0u;
  if (t == 0) s_ccnt = 0;
  __syncthreads();

  // pass 1: histogram (coalesced loads)
  unsigned ub[C];
#pragma unroll
  for (int j = 0; j < C; ++j) {
    int idx = j * 1024 + t;
    if (idx < kNS) {
      unsigned u = __float_as_uint(pl_b[idx]) & 0x7fffffffu;
      ub[j] = u;
      atomicAdd(&hist[u >> 17], 1u);
    } else {
      ub[j] = 0xffffffffu;
    }
  }
  __syncthreads();

  // scan: each thread sums 16 bins, then inclusive Hillis-Steele over 1024
  unsigned s = 0;
#pragma unroll
  for (int k = 0; k < 16; ++k) s += hist[t * 16 + k];
  scan[t] = s;
  __syncthreads();
  for (int off = 1; off < 1024; off <<= 1) {
    unsigned v = (t >= off) ? scan[t - off] : 0u;
    __syncthreads();
    scan[t] += v;
    __syncthreads();
  }
  unsigned incl = scan[t];
  unsigned excl = incl - s;
  const unsigned K = (unsigned)kNUNC;
  if (excl < K && incl >= K) {       // exactly one thread
    unsigned cum = excl;
    int bs = t * 16 + 15;
    for (int k = 0; k < 16; ++k) {
      unsigned h = hist[t * 16 + k];
      if (cum + h >= K) { bs = t * 16 + k; break; }
      cum += h;
    }
    s_bstar = bs;
    s_need = (int)(K - cum);
  }
  __syncthreads();
  int bstar = s_bstar;
  int need = s_need;

  // pass 2: mark below-boundary bins; collect boundary-bin candidates
#pragma unroll
  for (int j = 0; j < C; ++j) {
    int idx = j * 1024 + t;
    if (idx < kNS) {
      int bin = (int)(ub[j] >> 17);
      unsigned char f = (bin < bstar) ? 1 : 0;
      if (bin == bstar) {
        int pos = atomicAdd(&s_ccnt, 1);
        if (pos < CAP) cand[pos] = idx;
      }
      sel_b[idx] = f;
    }
  }
  __syncthreads();
  int c = s_ccnt;

  if (c <= CAP) {
    // rank boundary candidates by index; take the first `need`
    for (int i = t; i < c; i += 1024) {
      int my = cand[i];
      int r = 0;
      for (int k = 0; k < c; ++k) r += (cand[k] < my) ? 1 : 0;
      if (r < need) sel_b[my] = 1;
    }
  } else {
    // deterministic ordered-scan fallback (pathological duplicate-heavy data)
    if (t == 0) s_round = 0;
    __syncthreads();
    for (int j = 0; j < C; ++j) {
      int idx = j * 1024 + t;
      unsigned flag = (idx < kNS && (int)(ub[j] >> 17) == bstar) ? 1u : 0u;
      scan[t] = flag;
      __syncthreads();
      for (int off = 1; off < 1024; off <<= 1) {
        unsigned v = (t >= off) ? scan[t - off] : 0u;
        __syncthreads();
        scan[t] += v;
        __syncthreads();
      }
      int base = s_round;
      if (flag && base + (int)(scan[t] - flag) < need) sel_b[idx] = 1;
      __syncthreads();
      if (t == 0) s_round = base + (int)scan[1023];
      __syncthreads();
    }
  }
}

// ---- point CE + dice partial sums (plain stores, no atomics) ----
__global__ __launch_bounds__(256) void pointloss_kernel(const float* __restrict__ pred,
                                                        const float* __restrict__ gt,
                                                        const float* __restrict__ coords_os,
                                                        const float* __restrict__ coords_rand,
                                                        const float* __restrict__ pl,
                                                        const unsigned char* __restrict__ sel,
                                                        float* __restrict__ plp) {
  int b = blockIdx.x / kPLB;
  int c = blockIdx.x % kPLB;
  int t = threadIdx.x;
  const float* pred_b = pred + (size_t)b * kHW;
  const float* gt_b = gt + (size_t)b * kHW;
  float ce_s = 0.0f, p_s = 0.0f, t_s = 0.0f, pt_s = 0.0f;
  const int total = kNS + kNRAND;
  for (int e = c * 256 + t; e < total; e += kPLB * 256) {
    float cx, cy, z;
    if (e < kNS) {
      if (!sel[(size_t)b * kNS + e]) continue;
      float2 cc = *(const float2*)&coords_os[((size_t)b * kNS + e) * 2];
      cx = cc.x; cy = cc.y;
      z = pl[(size_t)b * kNS + e];
    } else {
      int j = e - kNS;
      float2 cc = *(const float2*)&coords_rand[((size_t)b * kNRAND + j) * 2];
      cx = cc.x; cy = cc.y;
      z = sample_bilinear(pred_b, cx, cy);
    }
    float tt = sample_bilinear(gt_b, cx, cy);
    float ce = fmaxf(z, 0.0f) - z * tt + log1pf(expf(-fabsf(z)));
    float a = expf(-fabsf(z));
    float inv = 1.0f / (1.0f + a);
    float p = (z >= 0.0f) ? inv : a * inv;
    ce_s += ce; p_s += p; t_s += tt; pt_s += p * tt;
  }
  __shared__ float red[4][256];
  red[0][t] = ce_s; red[1][t] = p_s; red[2][t] = t_s; red[3][t] = pt_s;
  __syncthreads();
  for (int s = 128; s > 0; s >>= 1) {
    if (t < s) {
      red[0][t] += red[0][t + s];
      red[1][t] += red[1][t + s];
      red[2][t] += red[2][t + s];
      red[3][t] += red[3][t + s];
    }
    __syncthreads();
  }
  if (t == 0) {
    float* o = plp + ((size_t)b * kPLB + c) * 4;
    o[0] = red[0][0]; o[1] = red[1][0]; o[2] = red[2][0]; o[3] = red[3][0];
  }
}

// ---- region BCE + dice partial sums; bbox derived inline from partials ----
__global__ __launch_bounds__(256) void region_kernel(const float* __restrict__ pred,
                                                     const float* __restrict__ gt,
                                                     const int* __restrict__ bbp,
                                                     float* __restrict__ rgp) {
  constexpr int CHUNK4 = kHW / kRGB / 4;  // 1024 float4 per block
  int b = blockIdx.x / kRGB;
  int c = blockIdx.x % kRGB;
  int t = threadIdx.x;
  const float4* pred4 = (const float4*)(pred + (size_t)b * kHW) + (size_t)c * CHUNK4;
  const float4* gt4 = (const float4*)(gt + (size_t)b * kHW) + (size_t)c * CHUNK4;

  // reduce 16 bbox partials
  int xmn = kW, xmx = -1, ymn = kH, ymx = -1;
#pragma unroll
  for (int q = 0; q < kBXB; ++q) {
    const int4 pb = *(const int4*)(bbp + ((size_t)b * kBXB + q) * 4);
    xmn = min(xmn, pb.x); xmx = max(xmx, pb.y);
    ymn = min(ymn, pb.z); ymx = max(ymx, pb.w);
  }
  bool empty = (xmx < 0);
  int x1 = empty ? 0 : xmn;
  int x2 = min(empty ? (kW - 1) : xmx, kW - 1);
  int y1 = empty ? 0 : ymn;
  int y2 = min(empty ? (kH - 1) : ymx, kH - 1);
  bool valid = (x2 > x1) && (y2 > y1);

  int pbase = c * CHUNK4 * 4;
  float wsum = 0.0f, bcew = 0.0f, inter = 0.0f, pw = 0.0f, gw = 0.0f;
  for (int i = t; i < CHUNK4; i += 256) {
    float4 zv = pred4[i];
    float4 gv = gt4[i];
    int p = pbase + i * 4;
    int y = p >> 9;
    int x0 = p & (kW - 1);
    bool iny = valid && (y >= y1) && (y <= y2);
#pragma unroll
    for (int l = 0; l < 4; ++l) {
      float z = (l == 0) ? zv.x : (l == 1) ? zv.y : (l == 2) ? zv.z : zv.w;
      float g = (l == 0) ? gv.x : (l == 1) ? gv.y : (l == 2) ? gv.z : gv.w;
      int x = x0 + l;
      float w = (iny && x >= x1 && x <= x2) ? 2.0f : 0.5f;
      float a = expf(-fabsf(z));
      float sp = fmaxf(-z, 0.0f) + log1pf(a);   // softplus(-z) = -log_sigmoid(z)
      float bce = sp + (1.0f - g) * z;
      float inv = 1.0f / (1.0f + a);
      float pp = (z >= 0.0f) ? inv : a * inv;
      wsum += w;
      bcew += bce * w;
      inter += pp * g * w;
      pw += pp * w;
      gw += g * w;
    }
  }
  __shared__ float red[5][256];
  red[0][t] = wsum; red[1][t] = bcew; red[2][t] = inter; red[3][t] = pw; red[4][t] = gw;
  __syncthreads();
  for (int s = 128; s > 0; s >>= 1) {
    if (t < s) {
#pragma unroll
      for (int q = 0; q < 5; ++q) red[q][t] += red[q][t + s];
    }
    __syncthreads();
  }
  if (t == 0) {
    float* o = rgp + ((size_t)b * kRGB + c) * 5;
    o[0] = red[0][0]; o[1] = red[1][0]; o[2] = red[2][0]; o[3] = red[3][0]; o[4] = red[4][0];
  }
}

// ---- finalize: reduce partials in f64 ----
__global__ __launch_bounds__(64) void finalize_kernel(const float* __restrict__ plp,
                                                      const float* __restrict__ rgp,
                                                      float* __restrict__ out) {
  __shared__ double sh[kB][4];
  int t = threadIdx.x;
  if (t < kB) {
    double ce = 0, p = 0, tt = 0, pt = 0;
    for (int c = 0; c < kPLB; ++c) {
      const float* q = plp + ((size_t)t * kPLB + c) * 4;
      ce += q[0]; p += q[1]; tt += q[2]; pt += q[3];
    }
    double ws = 0, bc = 0, in = 0, pw = 0, gw = 0;
    for (int c = 0; c < kRGB; ++c) {
      const float* q = rgp + ((size_t)t * kRGB + c) * 5;
      ws += q[0]; bc += q[1]; in += q[2]; pw += q[3]; gw += q[4];
    }
    sh[t][0] = ce / (double)kNPTS;
    sh[t][1] = 1.0 - (2.0 * pt + 1.0) / (p + tt + 1.0);
    double wss = ws > 1e-6 ? ws : 1e-6;
    sh[t][2] = bc / wss;
    sh[t][3] = 1.0 - (2.0 * in + 1.0) / (pw + gw + 1.0);
  }
  __syncthreads();
  if (t == 0) {
    double a = 0, b = 0, c = 0, d = 0;
    for (int i = 0; i < kB; ++i) { a += sh[i][0]; b += sh[i][1]; c += sh[i][2]; d += sh[i][3]; }
    out[0] = (float)(a / 16.0);
    out[1] = (float)(b / 16.0);
    out[2] = (float)(c / 16.0);
    out[3] = (float)(d / 16.0);
  }
}

extern "C" void kernel_launch(void* const* d_in, const int* in_sizes, int n_in,
                              void* d_out, int out_size, void* d_ws, size_t ws_size,
                              hipStream_t stream) {
  const float* pred = (const float*)d_in[0];
  const float* gt = (const float*)d_in[1];
  const float* coords_os = (const float*)d_in[2];
  const float* coords_rand = (const float*)d_in[3];
  float* out = (float*)d_out;
  char* ws = (char*)d_ws;

  float* pl = (float*)(ws + OFF_PL);
  unsigned char* sel = (unsigned char*)(ws + OFF_SEL);
  int* bbp = (int*)(ws + OFF_BBP);
  float* plp = (float*)(ws + OFF_PLP);
  float* rgp = (float*)(ws + OFF_RGP);

  sample_bbox_kernel<<<kSampleBlocks + kB * kBXB, 256, 0, stream>>>(pred, coords_os, pl, bbp);
  select_kernel<<<kB, 1024, 0, stream>>>(pl, sel);
  pointloss_kernel<<<kB * kPLB, 256, 0, stream>>>(pred, gt, coords_os, coords_rand, pl, sel, plp);
  region_kernel<<<kB * kRGB, 256, 0, stream>>>(pred, gt, bbp, rgp);
  finalize_kernel<<<1, 64, 0, stream>>>(plp, rgp, out);
}